// Round 4
// baseline (3610.628 us; speedup 1.0000x reference)
//
#include <hip/hip_runtime.h>
#include <hip/hip_bf16.h>

// ---------------------------------------------------------------------------
// TransportOperator: FISTA sparse coding through block-diag expm + transport.
// B=256, D=512, K=8, M=64, N=64.  20 FISTA iters, lr=0.01, lambda=0.05.
//
// dL/dT = sum_{j,l} u_j v_l^T / (j+l+1)!,  u_j=(T^T)^j r, v_l=T^l z0.
// Per iter: gemm1 (T = y*psi, MFMA, LDS-transpose epilogue) -> krylov
// (T in registers, DPP quad-reduce, NTERM=8; writes O bf16 over T) ->
// gemm2a (grid 1024 = 16bt x 8k x 8 uv-splits for occupancy; LDS reduce ->
// coalesced fp32 atomicAdd into g[16k]; LAST wg (ticket) applies the FISTA
// prox from g, writes c/y + bf16 mirrors, zeroes g + ticket).
// ---------------------------------------------------------------------------

typedef __attribute__((ext_vector_type(8))) short bf16x8;
typedef __attribute__((ext_vector_type(4))) float f32x4;
typedef unsigned short ushort_t;
typedef unsigned int uint_t;

#define NTERM 8   // Taylor orders 0..7; ||T||^8/8! <= 1e-7 << bf16 noise

__device__ __constant__ float INVF[20] = {
    1.0f, 1.0f, 0.5f, 1.6666666666666666e-1f, 4.1666666666666664e-2f,
    8.333333333333333e-3f, 1.3888888888888889e-3f, 1.984126984126984e-4f,
    2.48015873015873e-5f, 2.7557319223985893e-6f, 2.755731922398589e-7f,
    2.505210838544172e-8f, 2.08767569878681e-9f, 1.6059043836821613e-10f,
    1.1470745597729725e-11f, 7.647163731819816e-13f, 4.779477332387385e-14f,
    2.8114572543455206e-15f, 1.5619206968586225e-16f, 8.22063524662433e-18f};

__device__ __forceinline__ ushort_t f2b(float x) {
    uint_t u = __float_as_uint(x);
    uint_t r = u + 0x7FFFu + ((u >> 16) & 1u);   // RNE
    return (ushort_t)(r >> 16);
}
__device__ __forceinline__ float b2f(ushort_t h) {
    return __uint_as_float((uint_t)h << 16);
}

// quad sum via DPP (VALU pipe, no LDS ops)
__device__ __forceinline__ float qsum4(float s) {
    int a = __builtin_amdgcn_update_dpp(0, __float_as_int(s), 0xB1, 0xF, 0xF, true);
    s += __int_as_float(a);                       // xor 1
    int b = __builtin_amdgcn_update_dpp(0, __float_as_int(s), 0x4E, 0xF, 0xF, true);
    s += __int_as_float(b);                       // xor 2
    return s;
}

// --- one-time: psi fp32 -> psiB [k][m][uv] bf16 and psiT [j=k*4096+uv][m] --
__global__ __launch_bounds__(256) void prep_k(const float* __restrict__ psi,
                                              ushort_t* __restrict__ psiB,
                                              ushort_t* __restrict__ psiT) {
    int base = blockIdx.x * 2048 + threadIdx.x;
    for (int i = 0; i < 8; ++i) {
        int e = base + i * 256;                // e in [0, 2097152)
        float v = psi[e];
        ushort_t h = f2b(v);
        psiB[e] = h;
        int k = e >> 18;
        int r = e & 262143;
        int m = r >> 12;
        int uv = r & 4095;
        psiT[(size_t)k * 262144 + (size_t)uv * 64 + m] = h;
    }
}

// --- GEMM1: T[b][j] = sum_m y[b,m] * psiT[j,m].  D-rows <-> j. -------------
__global__ __launch_bounds__(256) void gemm1_k(const ushort_t* __restrict__ ybf,
                                               const ushort_t* __restrict__ psiT,
                                               ushort_t* __restrict__ Tbf) {
    __shared__ __align__(16) ushort_t Ls[256 * 72];   // [b 256][j 64] swizzled
    int j0 = blockIdx.x * 64;
    int tid = threadIdx.x;
    int wave = tid >> 6, lane = tid & 63;
    int rowi = lane & 15, q = lane >> 4;
    int b0w = wave * 64;

    f32x4 acc[4][4];
    const f32x4 zero = {0.f, 0.f, 0.f, 0.f};
    for (int ta = 0; ta < 4; ++ta)
        for (int tb = 0; tb < 4; ++tb) acc[ta][tb] = zero;

    for (int ks = 0; ks < 2; ++ks) {
        bf16x8 a[4], bb[4];
        for (int ta = 0; ta < 4; ++ta)
            a[ta] = *(const bf16x8*)(psiT + (size_t)(j0 + ta * 16 + rowi) * 64 +
                                     ks * 32 + q * 8);
        for (int tb = 0; tb < 4; ++tb)
            bb[tb] = *(const bf16x8*)(ybf + (size_t)(b0w + tb * 16 + rowi) * 64 +
                                      ks * 32 + q * 8);
        for (int ta = 0; ta < 4; ++ta)
            for (int tb = 0; tb < 4; ++tb)
                acc[ta][tb] = __builtin_amdgcn_mfma_f32_16x16x32_bf16(
                    a[ta], bb[tb], acc[ta][tb], 0, 0, 0);
    }
    for (int ta = 0; ta < 4; ++ta)
        for (int tb = 0; tb < 4; ++tb) {
            int bl = b0w + tb * 16 + rowi;
            int jl = ta * 16 + q * 4;
            uint_t lo = (uint_t)f2b(acc[ta][tb][0]) | ((uint_t)f2b(acc[ta][tb][1]) << 16);
            uint_t hi = (uint_t)f2b(acc[ta][tb][2]) | ((uint_t)f2b(acc[ta][tb][3]) << 16);
            int idx = bl * 72 + ((((jl >> 3) + 2 * bl) & 7) << 3) + (jl & 7);
            *(uint2*)&Ls[idx] = make_uint2(lo, hi);
        }
    __syncthreads();
    for (int pass = 0; pass < 8; ++pass) {
        int b = pass * 32 + (tid >> 3);
        int ch = tid & 7;
        uint4 v = *(const uint4*)&Ls[b * 72 + ch * 8];
        int x = (ch - 2 * b) & 7;
        *(uint4*)(Tbf + (size_t)b * 32768 + j0 + x * 8) = v;
    }
}

// --- Krylov: per (b,k); T in registers; grad mode writes O over T. ---------
__global__ __launch_bounds__(256) void krylov_k(const ushort_t* __restrict__ Tbf,
                                                const float* __restrict__ z0,
                                                const float* __restrict__ z1,
                                                ushort_t* __restrict__ Obf,
                                                float* __restrict__ out) {
    __shared__ float V[NTERM][64];
    __shared__ float U[NTERM][64];
    __shared__ float zz[64];
    int bid = blockIdx.x;
    int b = bid >> 3, k = bid & 7;
    int tid = threadIdx.x;
    int row = tid >> 2, p = tid & 3, c0 = p * 16;
    bool grad = (out == nullptr);

    const ushort_t* tbase = Tbf + (size_t)bid * 4096;
    float rowT[16];
    {
        uint4 ra = *(const uint4*)(tbase + row * 64 + c0);
        uint4 rb = *(const uint4*)(tbase + row * 64 + c0 + 8);
        uint_t wv[8] = {ra.x, ra.y, ra.z, ra.w, rb.x, rb.y, rb.z, rb.w};
        for (int i = 0; i < 8; ++i) {
            rowT[2 * i]     = __uint_as_float(wv[i] << 16);
            rowT[2 * i + 1] = __uint_as_float(wv[i] & 0xFFFF0000u);
        }
    }
    float colT[16];
    if (grad) {
#pragma unroll
        for (int i = 0; i < 16; ++i) colT[i] = b2f(tbase[(c0 + i) * 64 + row]);
    }
    if (tid < 64) {
        V[0][tid] = z0[(size_t)b * 512 + k * 64 + tid];
        zz[tid]   = z1[(size_t)b * 512 + k * 64 + tid];
    }
    __syncthreads();

    // v series
    for (int l = 1; l < NTERM; ++l) {
        const f32x4* vp = (const f32x4*)&V[l - 1][c0];
        f32x4 v0 = vp[0], v1 = vp[1], v2 = vp[2], v3 = vp[3];
        float s0 = 0.f, s1 = 0.f, s2 = 0.f, s3 = 0.f;
#pragma unroll
        for (int i = 0; i < 4; ++i) {
            s0 = fmaf(rowT[i], v0[i], s0);
            s1 = fmaf(rowT[4 + i], v1[i], s1);
            s2 = fmaf(rowT[8 + i], v2[i], s2);
            s3 = fmaf(rowT[12 + i], v3[i], s3);
        }
        float s = qsum4((s0 + s1) + (s2 + s3));
        if (p == 0) V[l][row] = s;
        __syncthreads();
    }

    if (!grad) {
        if (tid < 64) {
            float zh = 0.f;
#pragma unroll
            for (int l = 0; l < NTERM; ++l) zh = fmaf(INVF[l], V[l][tid], zh);
            out[(size_t)b * 512 + k * 64 + tid] = zh;
        }
        return;
    }

    if (tid < 64) {
        float zh = 0.f;
#pragma unroll
        for (int l = 0; l < NTERM; ++l) zh = fmaf(INVF[l], V[l][tid], zh);
        U[0][tid] = zh - zz[tid];
    }
    __syncthreads();

    // u series (T^T via colT)
    for (int j = 1; j < NTERM; ++j) {
        const f32x4* up = (const f32x4*)&U[j - 1][c0];
        f32x4 u0 = up[0], u1 = up[1], u2 = up[2], u3 = up[3];
        float s0 = 0.f, s1 = 0.f, s2 = 0.f, s3 = 0.f;
#pragma unroll
        for (int i = 0; i < 4; ++i) {
            s0 = fmaf(colT[i], u0[i], s0);
            s1 = fmaf(colT[4 + i], u1[i], s1);
            s2 = fmaf(colT[8 + i], u2[i], s2);
            s3 = fmaf(colT[12 + i], u3[i], s3);
        }
        float s = qsum4((s0 + s1) + (s2 + s3));
        if (p == 0) U[j][row] = s;
        __syncthreads();
    }

    // O[row][c0..c0+15] = sum_l W[l] * V[l][c]
    float W[NTERM];
#pragma unroll
    for (int l = 0; l < NTERM; ++l) {
        float w = 0.f;
#pragma unroll
        for (int j = 0; j < NTERM; ++j) w = fmaf(INVF[j + l + 1], U[j][row], w);
        W[l] = w;
    }
    float o[16];
#pragma unroll
    for (int i = 0; i < 16; ++i) o[i] = 0.f;
#pragma unroll
    for (int l = 0; l < NTERM; ++l) {
        const f32x4* vp = (const f32x4*)&V[l][c0];
        f32x4 a0 = vp[0], a1 = vp[1], a2 = vp[2], a3 = vp[3];
        float w = W[l];
#pragma unroll
        for (int i = 0; i < 4; ++i) {
            o[i]      = fmaf(w, a0[i], o[i]);
            o[4 + i]  = fmaf(w, a1[i], o[4 + i]);
            o[8 + i]  = fmaf(w, a2[i], o[8 + i]);
            o[12 + i] = fmaf(w, a3[i], o[12 + i]);
        }
    }
    uint_t ow[8];
#pragma unroll
    for (int i = 0; i < 8; ++i)
        ow[i] = (uint_t)f2b(o[2 * i]) | ((uint_t)f2b(o[2 * i + 1]) << 16);
    uint4* op = (uint4*)(Obf + (size_t)bid * 4096 + row * 64 + c0);
    op[0] = make_uint4(ow[0], ow[1], ow[2], ow[3]);
    op[1] = make_uint4(ow[4], ow[5], ow[6], ow[7]);
}

// --- GEMM2 + fused FISTA.  grid 1024 = (16 bt) x (8 k) x (8 uv-splits). ----
// wg: 16 b x 64 m x 512 uv; 4 waves split uv.  LDS reduce -> fp32 atomicAdd
// into g[b][m].  Last wg (ticket) applies prox, zeroes g + ticket.
__global__ __launch_bounds__(256) void gemm2a_k(const ushort_t* __restrict__ Obf,
                                                const ushort_t* __restrict__ psiB,
                                                float* __restrict__ g,
                                                float* __restrict__ cb,
                                                float* __restrict__ yb,
                                                ushort_t* __restrict__ cbf,
                                                ushort_t* __restrict__ ybf,
                                                uint_t* __restrict__ cnt,
                                                int iter) {
    __shared__ __align__(16) float Lg[16 * 68];   // [b 16][m 64] stride 68
    __shared__ uint_t ticket;
    int wg = blockIdx.x;
    int bt = wg & 15;                  // 16 b-tiles of 16
    int k = (wg >> 4) & 7;             // 8 blocks
    int sp = wg >> 7;                  // 8 uv-splits of 512
    int tid = threadIdx.x, wave = tid >> 6, lane = tid & 63;
    int rowi = lane & 15, q = lane >> 4;

    f32x4 acc[4];
    const f32x4 zero = {0.f, 0.f, 0.f, 0.f};
    for (int ta = 0; ta < 4; ++ta) acc[ta] = zero;

    int off0 = sp * 512 + wave * 128 + q * 8;
    const ushort_t* ob = Obf + (size_t)(bt * 16 + rowi) * 32768 + k * 4096 + off0;
    const ushort_t* pb = psiB + (size_t)k * 262144 + (size_t)rowi * 4096 + off0;
#pragma unroll
    for (int ks = 0; ks < 4; ++ks) {
        bf16x8 bb = *(const bf16x8*)(ob + ks * 32);
#pragma unroll
        for (int ta = 0; ta < 4; ++ta) {
            bf16x8 a = *(const bf16x8*)(pb + (size_t)ta * 65536 + ks * 32);
            acc[ta] = __builtin_amdgcn_mfma_f32_16x16x32_bf16(a, bb, acc[ta], 0, 0, 0);
        }
    }
    // inter-wave reduce; D[row = m-frag q*4+r][col = b-frag rowi]
    for (int w = 0; w < 4; ++w) {
        if (wave == w) {
            for (int ta = 0; ta < 4; ++ta) {
                float* dst = &Lg[rowi * 68 + ta * 16 + q * 4];
                if (w == 0) *(f32x4*)dst = acc[ta];
                else {
                    f32x4 t = *(const f32x4*)dst;
                    t += acc[ta];
                    *(f32x4*)dst = t;
                }
            }
        }
        __syncthreads();
    }
    {   // coalesced atomic adds: thread -> (b = tid>>4, m4 = (tid&15)*4)
        int b = tid >> 4, m4 = (tid & 15) * 4;
        const float* lp = &Lg[b * 68 + m4];
        float* gp = g + (size_t)(bt * 16 + b) * 64 + m4;
        atomicAdd(gp + 0, lp[0]);
        atomicAdd(gp + 1, lp[1]);
        atomicAdd(gp + 2, lp[2]);
        atomicAdd(gp + 3, lp[3]);
    }
    __threadfence();
    if (tid == 0) ticket = atomicAdd(cnt, 1u);
    __syncthreads();
    if (ticket != 1023u) return;
    __threadfence();

    // ---- last wg: FISTA prox over all 16384 (b,m) ----
    float t = 1.f;
    for (int s = 0; s < iter; ++s) t = 0.5f * (1.f + sqrtf(1.f + 4.f * t * t));
    float tn = 0.5f * (1.f + sqrtf(1.f + 4.f * t * t));
    float beta = (t - 1.f) / tn;
    const float lr = 0.01f, thr = 0.01f * 0.05f;
    for (int idx = tid; idx < 16384; idx += 256) {
        float gv = __hip_atomic_load(&g[idx], __ATOMIC_RELAXED,
                                     __HIP_MEMORY_SCOPE_AGENT);
        float co = cb[idx], yo = yb[idx];
        float a = yo - lr * gv;
        float c = copysignf(fmaxf(fabsf(a) - thr, 0.f), a);
        float yn = c + beta * (c - co);
        cb[idx] = c;
        yb[idx] = yn;
        cbf[idx] = f2b(c);
        ybf[idx] = f2b(yn);
        g[idx] = 0.f;                  // re-zero for next iteration
    }
    __threadfence();
    if (tid == 0)
        __hip_atomic_store(cnt, 0u, __ATOMIC_RELAXED, __HIP_MEMORY_SCOPE_AGENT);
}

extern "C" void kernel_launch(void* const* d_in, const int* in_sizes, int n_in,
                              void* d_out, int out_size, void* d_ws, size_t ws_size,
                              hipStream_t stream) {
    const float* z0 = (const float*)d_in[0];
    const float* z1 = (const float*)d_in[1];
    const float* psi = (const float*)d_in[2];
    float* out = (float*)d_out;

    char* w = (char*)d_ws;
    ushort_t* TO    = (ushort_t*)(w);                 // 16,777,216  (T, then O)
    ushort_t* psiB  = (ushort_t*)(w + 16777216);      //  4,194,304
    ushort_t* psiT  = (ushort_t*)(w + 20971520);      //  4,194,304
    float*    gbuf  = (float*)(w + 25165824);         //     65,536
    float*    cbuf  = (float*)(w + 25231360);         //     65,536
    float*    ybuf  = (float*)(w + 25296896);         //     65,536
    ushort_t* cbf   = (ushort_t*)(w + 25362432);      //     32,768
    ushort_t* ybf   = (ushort_t*)(w + 25395200);      //     32,768
    uint_t*   cnt   = (uint_t*)(w + 25427968);        //          4
    // total < 26 MB

    // zero g, c, y (fp32+bf16) and the ticket counter in one contiguous shot
    hipMemsetAsync(w + 25165824, 0, 262148, stream);

    prep_k<<<1024, 256, 0, stream>>>(psi, psiB, psiT);

    for (int it = 0; it < 20; ++it) {
        gemm1_k<<<512, 256, 0, stream>>>(ybf, psiT, TO);
        krylov_k<<<2048, 256, 0, stream>>>(TO, z0, z1, TO, nullptr);
        gemm2a_k<<<1024, 256, 0, stream>>>(TO, psiB, gbuf, cbuf, ybuf, cbf, ybf,
                                           cnt, it);
    }

    gemm1_k<<<512, 256, 0, stream>>>(cbf, psiT, TO);
    krylov_k<<<2048, 256, 0, stream>>>(TO, z0, z1, TO, out);
}

// Round 5
// 882.560 us; speedup vs baseline: 4.0911x; 4.0911x over previous
//
#include <hip/hip_runtime.h>
#include <hip/hip_bf16.h>

// ---------------------------------------------------------------------------
// TransportOperator: FISTA sparse coding through block-diag expm + transport.
// B=256, D=512, K=8, M=64, N=64.  20 FISTA iters, lr=0.01, lambda=0.05.
//
// dL/dT = sum_{j,l} u_j v_l^T / (j+l+1)!,  u_j=(T^T)^j r, v_l=T^l z0.
// Per iter: gemm1 (T = y*psi, MFMA, LDS-transpose epilogue) -> krylov
// (T in registers, DPP quad-reduce, NTERM=8; writes O bf16 over T) ->
// gemm2 (64 split-K partials, MFMA, LDS reduce, NO atomics) -> fista_update
// (parallel 64-partial reduction + prox).  [R3/R4 lesson: low-occupancy
// full-K gemm2 and 64-way atomic contention both lose >2x; partials win.]
// ---------------------------------------------------------------------------

typedef __attribute__((ext_vector_type(8))) short bf16x8;
typedef __attribute__((ext_vector_type(4))) float f32x4;
typedef unsigned short ushort_t;
typedef unsigned int uint_t;

#define NTERM 8   // Taylor orders 0..7; ||T||^8/8! <= 1e-7 << bf16 noise

__device__ __constant__ float INVF[20] = {
    1.0f, 1.0f, 0.5f, 1.6666666666666666e-1f, 4.1666666666666664e-2f,
    8.333333333333333e-3f, 1.3888888888888889e-3f, 1.984126984126984e-4f,
    2.48015873015873e-5f, 2.7557319223985893e-6f, 2.755731922398589e-7f,
    2.505210838544172e-8f, 2.08767569878681e-9f, 1.6059043836821613e-10f,
    1.1470745597729725e-11f, 7.647163731819816e-13f, 4.779477332387385e-14f,
    2.8114572543455206e-15f, 1.5619206968586225e-16f, 8.22063524662433e-18f};

__device__ __forceinline__ ushort_t f2b(float x) {
    uint_t u = __float_as_uint(x);
    uint_t r = u + 0x7FFFu + ((u >> 16) & 1u);   // RNE
    return (ushort_t)(r >> 16);
}
__device__ __forceinline__ float b2f(ushort_t h) {
    return __uint_as_float((uint_t)h << 16);
}

// quad sum via DPP (VALU pipe, no LDS ops)
__device__ __forceinline__ float qsum4(float s) {
    int a = __builtin_amdgcn_update_dpp(0, __float_as_int(s), 0xB1, 0xF, 0xF, true);
    s += __int_as_float(a);                       // xor 1
    int b = __builtin_amdgcn_update_dpp(0, __float_as_int(s), 0x4E, 0xF, 0xF, true);
    s += __int_as_float(b);                       // xor 2
    return s;
}

// --- one-time: psi fp32 -> psiB [k][m][uv] bf16 and psiT [j=k*4096+uv][m] --
__global__ __launch_bounds__(256) void prep_k(const float* __restrict__ psi,
                                              ushort_t* __restrict__ psiB,
                                              ushort_t* __restrict__ psiT) {
    int base = blockIdx.x * 2048 + threadIdx.x;
    for (int i = 0; i < 8; ++i) {
        int e = base + i * 256;                // e in [0, 2097152)
        float v = psi[e];
        ushort_t h = f2b(v);
        psiB[e] = h;
        int k = e >> 18;
        int r = e & 262143;
        int m = r >> 12;
        int uv = r & 4095;
        psiT[(size_t)k * 262144 + (size_t)uv * 64 + m] = h;
    }
}

// --- GEMM1: T[b][j] = sum_m y[b,m] * psiT[j,m].  D-rows <-> j. -------------
__global__ __launch_bounds__(256) void gemm1_k(const ushort_t* __restrict__ ybf,
                                               const ushort_t* __restrict__ psiT,
                                               ushort_t* __restrict__ Tbf) {
    __shared__ __align__(16) ushort_t Ls[256 * 72];   // [b 256][j 64] swizzled
    int j0 = blockIdx.x * 64;
    int tid = threadIdx.x;
    int wave = tid >> 6, lane = tid & 63;
    int rowi = lane & 15, q = lane >> 4;
    int b0w = wave * 64;

    f32x4 acc[4][4];
    const f32x4 zero = {0.f, 0.f, 0.f, 0.f};
    for (int ta = 0; ta < 4; ++ta)
        for (int tb = 0; tb < 4; ++tb) acc[ta][tb] = zero;

    for (int ks = 0; ks < 2; ++ks) {
        bf16x8 a[4], bb[4];
        for (int ta = 0; ta < 4; ++ta)
            a[ta] = *(const bf16x8*)(psiT + (size_t)(j0 + ta * 16 + rowi) * 64 +
                                     ks * 32 + q * 8);
        for (int tb = 0; tb < 4; ++tb)
            bb[tb] = *(const bf16x8*)(ybf + (size_t)(b0w + tb * 16 + rowi) * 64 +
                                      ks * 32 + q * 8);
        for (int ta = 0; ta < 4; ++ta)
            for (int tb = 0; tb < 4; ++tb)
                acc[ta][tb] = __builtin_amdgcn_mfma_f32_16x16x32_bf16(
                    a[ta], bb[tb], acc[ta][tb], 0, 0, 0);
    }
    for (int ta = 0; ta < 4; ++ta)
        for (int tb = 0; tb < 4; ++tb) {
            int bl = b0w + tb * 16 + rowi;
            int jl = ta * 16 + q * 4;
            uint_t lo = (uint_t)f2b(acc[ta][tb][0]) | ((uint_t)f2b(acc[ta][tb][1]) << 16);
            uint_t hi = (uint_t)f2b(acc[ta][tb][2]) | ((uint_t)f2b(acc[ta][tb][3]) << 16);
            int idx = bl * 72 + ((((jl >> 3) + 2 * bl) & 7) << 3) + (jl & 7);
            *(uint2*)&Ls[idx] = make_uint2(lo, hi);
        }
    __syncthreads();
    for (int pass = 0; pass < 8; ++pass) {
        int b = pass * 32 + (tid >> 3);
        int ch = tid & 7;
        uint4 v = *(const uint4*)&Ls[b * 72 + ch * 8];
        int x = (ch - 2 * b) & 7;
        *(uint4*)(Tbf + (size_t)b * 32768 + j0 + x * 8) = v;
    }
}

// --- Krylov: per (b,k); T in registers; grad mode writes O over T. ---------
__global__ __launch_bounds__(256) void krylov_k(const ushort_t* __restrict__ Tbf,
                                                const float* __restrict__ z0,
                                                const float* __restrict__ z1,
                                                ushort_t* __restrict__ Obf,
                                                float* __restrict__ out) {
    __shared__ float V[NTERM][64];
    __shared__ float U[NTERM][64];
    __shared__ float zz[64];
    int bid = blockIdx.x;
    int b = bid >> 3, k = bid & 7;
    int tid = threadIdx.x;
    int row = tid >> 2, p = tid & 3, c0 = p * 16;
    bool grad = (out == nullptr);

    const ushort_t* tbase = Tbf + (size_t)bid * 4096;
    float rowT[16];
    {
        uint4 ra = *(const uint4*)(tbase + row * 64 + c0);
        uint4 rb = *(const uint4*)(tbase + row * 64 + c0 + 8);
        uint_t wv[8] = {ra.x, ra.y, ra.z, ra.w, rb.x, rb.y, rb.z, rb.w};
        for (int i = 0; i < 8; ++i) {
            rowT[2 * i]     = __uint_as_float(wv[i] << 16);
            rowT[2 * i + 1] = __uint_as_float(wv[i] & 0xFFFF0000u);
        }
    }
    float colT[16];
    if (grad) {
#pragma unroll
        for (int i = 0; i < 16; ++i) colT[i] = b2f(tbase[(c0 + i) * 64 + row]);
    }
    if (tid < 64) {
        V[0][tid] = z0[(size_t)b * 512 + k * 64 + tid];
        zz[tid]   = z1[(size_t)b * 512 + k * 64 + tid];
    }
    __syncthreads();

    // v series
    for (int l = 1; l < NTERM; ++l) {
        const f32x4* vp = (const f32x4*)&V[l - 1][c0];
        f32x4 v0 = vp[0], v1 = vp[1], v2 = vp[2], v3 = vp[3];
        float s0 = 0.f, s1 = 0.f, s2 = 0.f, s3 = 0.f;
#pragma unroll
        for (int i = 0; i < 4; ++i) {
            s0 = fmaf(rowT[i], v0[i], s0);
            s1 = fmaf(rowT[4 + i], v1[i], s1);
            s2 = fmaf(rowT[8 + i], v2[i], s2);
            s3 = fmaf(rowT[12 + i], v3[i], s3);
        }
        float s = qsum4((s0 + s1) + (s2 + s3));
        if (p == 0) V[l][row] = s;
        __syncthreads();
    }

    if (!grad) {
        if (tid < 64) {
            float zh = 0.f;
#pragma unroll
            for (int l = 0; l < NTERM; ++l) zh = fmaf(INVF[l], V[l][tid], zh);
            out[(size_t)b * 512 + k * 64 + tid] = zh;
        }
        return;
    }

    if (tid < 64) {
        float zh = 0.f;
#pragma unroll
        for (int l = 0; l < NTERM; ++l) zh = fmaf(INVF[l], V[l][tid], zh);
        U[0][tid] = zh - zz[tid];
    }
    __syncthreads();

    // u series (T^T via colT)
    for (int j = 1; j < NTERM; ++j) {
        const f32x4* up = (const f32x4*)&U[j - 1][c0];
        f32x4 u0 = up[0], u1 = up[1], u2 = up[2], u3 = up[3];
        float s0 = 0.f, s1 = 0.f, s2 = 0.f, s3 = 0.f;
#pragma unroll
        for (int i = 0; i < 4; ++i) {
            s0 = fmaf(colT[i], u0[i], s0);
            s1 = fmaf(colT[4 + i], u1[i], s1);
            s2 = fmaf(colT[8 + i], u2[i], s2);
            s3 = fmaf(colT[12 + i], u3[i], s3);
        }
        float s = qsum4((s0 + s1) + (s2 + s3));
        if (p == 0) U[j][row] = s;
        __syncthreads();
    }

    // O[row][c0..c0+15] = sum_l W[l] * V[l][c]
    float W[NTERM];
#pragma unroll
    for (int l = 0; l < NTERM; ++l) {
        float w = 0.f;
#pragma unroll
        for (int j = 0; j < NTERM; ++j) w = fmaf(INVF[j + l + 1], U[j][row], w);
        W[l] = w;
    }
    float o[16];
#pragma unroll
    for (int i = 0; i < 16; ++i) o[i] = 0.f;
#pragma unroll
    for (int l = 0; l < NTERM; ++l) {
        const f32x4* vp = (const f32x4*)&V[l][c0];
        f32x4 a0 = vp[0], a1 = vp[1], a2 = vp[2], a3 = vp[3];
        float w = W[l];
#pragma unroll
        for (int i = 0; i < 4; ++i) {
            o[i]      = fmaf(w, a0[i], o[i]);
            o[4 + i]  = fmaf(w, a1[i], o[4 + i]);
            o[8 + i]  = fmaf(w, a2[i], o[8 + i]);
            o[12 + i] = fmaf(w, a3[i], o[12 + i]);
        }
    }
    uint_t ow[8];
#pragma unroll
    for (int i = 0; i < 8; ++i)
        ow[i] = (uint_t)f2b(o[2 * i]) | ((uint_t)f2b(o[2 * i + 1]) << 16);
    uint4* op = (uint4*)(Obf + (size_t)bid * 4096 + row * 64 + c0);
    op[0] = make_uint4(ow[0], ow[1], ow[2], ow[3]);
    op[1] = make_uint4(ow[4], ow[5], ow[6], ow[7]);
}

// --- GEMM2: gpart[kc][b][m] = sum_{uv in chunk} O[b][.] psiB[m][.] ---------
// grid 256 = 4 bt x 64 kc; 4 waves split the 512-long K-chunk; LDS reduce.
// [R2-measured-good: 1024 waves, 32 loads/wave, no atomics.]
__global__ __launch_bounds__(256) void gemm2_k(const ushort_t* __restrict__ Obf,
                                               const ushort_t* __restrict__ psiB,
                                               float* __restrict__ gpart) {
    __shared__ __align__(16) float Lg[64 * 68];    // [b 64][m 64] stride 68
    int bt = blockIdx.x & 3;
    int kc = blockIdx.x >> 2;          // 0..63
    int k = kc >> 3;
    int uv0 = (kc & 7) * 512;
    int tid = threadIdx.x, wave = tid >> 6, lane = tid & 63;
    int rowi = lane & 15, q = lane >> 4;

    f32x4 acc[4][4];
    const f32x4 zero = {0.f, 0.f, 0.f, 0.f};
    for (int ta = 0; ta < 4; ++ta)
        for (int tb = 0; tb < 4; ++tb) acc[ta][tb] = zero;

    for (int ks = 0; ks < 4; ++ks) {
        int off = uv0 + wave * 128 + ks * 32 + q * 8;
        bf16x8 a[4], bb[4];
        for (int ta = 0; ta < 4; ++ta)
            a[ta] = *(const bf16x8*)(psiB + (size_t)k * 262144 +
                                     (size_t)(ta * 16 + rowi) * 4096 + off);
        for (int tb = 0; tb < 4; ++tb)
            bb[tb] = *(const bf16x8*)(Obf +
                                      (size_t)(bt * 64 + tb * 16 + rowi) * 32768 +
                                      k * 4096 + off);
        for (int ta = 0; ta < 4; ++ta)
            for (int tb = 0; tb < 4; ++tb)
                acc[ta][tb] = __builtin_amdgcn_mfma_f32_16x16x32_bf16(
                    a[ta], bb[tb], acc[ta][tb], 0, 0, 0);
    }
    // sequential inter-wave reduce: D[row=mfrag][col=bfrag]
    for (int w = 0; w < 4; ++w) {
        if (wave == w) {
            for (int ta = 0; ta < 4; ++ta)
                for (int tb = 0; tb < 4; ++tb) {
                    float* dst = &Lg[(tb * 16 + rowi) * 68 + ta * 16 + q * 4];
                    if (w == 0) *(f32x4*)dst = acc[ta][tb];
                    else {
                        f32x4 t = *(const f32x4*)dst;
                        t += acc[ta][tb];
                        *(f32x4*)dst = t;
                    }
                }
        }
        __syncthreads();
    }
    int b = tid >> 2, mq = tid & 3;
    float* gp = gpart + (size_t)kc * 16384 + (size_t)(bt * 64 + b) * 64 + mq * 16;
    const float* lp = &Lg[b * 68 + mq * 16];
    for (int i = 0; i < 4; ++i)
        *(f32x4*)(gp + 4 * i) = *(const f32x4*)(lp + 4 * i);
}

// --- FISTA: reduce 64 partials + prox step; maintain fp32 + bf16 state -----
__global__ __launch_bounds__(256) void fista_update(const float* __restrict__ gpart,
                                                    float* __restrict__ cb,
                                                    float* __restrict__ yb,
                                                    ushort_t* __restrict__ cbf,
                                                    ushort_t* __restrict__ ybf,
                                                    int iter) {
    int idx = blockIdx.x * 256 + threadIdx.x;
    float a0 = 0.f, a1 = 0.f, a2 = 0.f, a3 = 0.f;
#pragma unroll
    for (int p = 0; p < 64; p += 4) {
        a0 += gpart[(size_t)p * 16384 + idx];
        a1 += gpart[(size_t)(p + 1) * 16384 + idx];
        a2 += gpart[(size_t)(p + 2) * 16384 + idx];
        a3 += gpart[(size_t)(p + 3) * 16384 + idx];
    }
    float gv = (a0 + a1) + (a2 + a3);
    float t = 1.f;
    for (int s = 0; s < iter; ++s) t = 0.5f * (1.f + sqrtf(1.f + 4.f * t * t));
    float tn = 0.5f * (1.f + sqrtf(1.f + 4.f * t * t));
    float beta = (t - 1.f) / tn;
    float co = cb[idx], yo = yb[idx];
    float a = yo - 0.01f * gv;
    float thr = 0.01f * 0.05f;
    float cn = copysignf(fmaxf(fabsf(a) - thr, 0.f), a);
    float yn = cn + beta * (cn - co);
    cb[idx] = cn;
    yb[idx] = yn;
    cbf[idx] = f2b(cn);
    ybf[idx] = f2b(yn);
}

extern "C" void kernel_launch(void* const* d_in, const int* in_sizes, int n_in,
                              void* d_out, int out_size, void* d_ws, size_t ws_size,
                              hipStream_t stream) {
    const float* z0 = (const float*)d_in[0];
    const float* z1 = (const float*)d_in[1];
    const float* psi = (const float*)d_in[2];
    float* out = (float*)d_out;

    char* w = (char*)d_ws;
    ushort_t* TO    = (ushort_t*)(w);                 // 16,777,216  (T, then O)
    ushort_t* psiB  = (ushort_t*)(w + 16777216);      //  4,194,304
    ushort_t* psiT  = (ushort_t*)(w + 20971520);      //  4,194,304
    float*    gpart = (float*)(w + 25165824);         //  4,194,304  (64 partials)
    float*    cbuf  = (float*)(w + 29360128);         //     65,536
    float*    ybuf  = (float*)(w + 29425664);         //     65,536
    ushort_t* cbf   = (ushort_t*)(w + 29491200);      //     32,768
    ushort_t* ybf   = (ushort_t*)(w + 29523968);      //     32,768
    // total 29,556,736 B

    hipMemsetAsync(w + 29360128, 0, 196608, stream);  // zero c,y state

    prep_k<<<1024, 256, 0, stream>>>(psi, psiB, psiT);

    for (int it = 0; it < 20; ++it) {
        gemm1_k<<<512, 256, 0, stream>>>(ybf, psiT, TO);
        krylov_k<<<2048, 256, 0, stream>>>(TO, z0, z1, TO, nullptr);
        gemm2_k<<<256, 256, 0, stream>>>(TO, psiB, gpart);
        fista_update<<<64, 256, 0, stream>>>(gpart, cbuf, ybuf, cbf, ybf, it);
    }

    gemm1_k<<<512, 256, 0, stream>>>(cbf, psiT, TO);
    krylov_k<<<2048, 256, 0, stream>>>(TO, z0, z1, TO, out);
}

// Round 6
// 865.071 us; speedup vs baseline: 4.1738x; 1.0202x over previous
//
#include <hip/hip_runtime.h>
#include <hip/hip_bf16.h>

// ---------------------------------------------------------------------------
// TransportOperator: FISTA sparse coding through block-diag expm + transport.
// B=256, D=512, K=8, M=64, N=64.  20 FISTA iters, lr=0.01, lambda=0.05.
//
// dL/dT = sum_{j,l} u_j v_l^T / (j+l+1)!,  u_j=(T^T)^j r, v_l=T^l z0.
// Per iter: gemm1 (T = y*psi, MFMA, LDS-transpose epilogue; grid 1024 for
// 8 wg/CU occupancy) -> krylov<6> (T in registers, DPP quad-reduce; grad
// precision slack: ||T||^6/6! ~ 1e-6 << bf16 noise; writes O over T) ->
// gemm2 (64 split-K partials, MFMA, LDS reduce, NO atomics) -> fista_update.
// Final: gemm1 + krylov<8> apply (output error is final-apply bf16 bound).
// [R3/R4 lessons: low-occupancy full-K gemm2 and 64-way atomic contention
// both lose >2x; split-K partials + parallel reduce win.]
// ---------------------------------------------------------------------------

typedef __attribute__((ext_vector_type(8))) short bf16x8;
typedef __attribute__((ext_vector_type(4))) float f32x4;
typedef unsigned short ushort_t;
typedef unsigned int uint_t;

__device__ __constant__ float INVF[20] = {
    1.0f, 1.0f, 0.5f, 1.6666666666666666e-1f, 4.1666666666666664e-2f,
    8.333333333333333e-3f, 1.3888888888888889e-3f, 1.984126984126984e-4f,
    2.48015873015873e-5f, 2.7557319223985893e-6f, 2.755731922398589e-7f,
    2.505210838544172e-8f, 2.08767569878681e-9f, 1.6059043836821613e-10f,
    1.1470745597729725e-11f, 7.647163731819816e-13f, 4.779477332387385e-14f,
    2.8114572543455206e-15f, 1.5619206968586225e-16f, 8.22063524662433e-18f};

__device__ __forceinline__ ushort_t f2b(float x) {
    uint_t u = __float_as_uint(x);
    uint_t r = u + 0x7FFFu + ((u >> 16) & 1u);   // RNE
    return (ushort_t)(r >> 16);
}
__device__ __forceinline__ float b2f(ushort_t h) {
    return __uint_as_float((uint_t)h << 16);
}

// quad sum via DPP (VALU pipe, no LDS ops)
__device__ __forceinline__ float qsum4(float s) {
    int a = __builtin_amdgcn_update_dpp(0, __float_as_int(s), 0xB1, 0xF, 0xF, true);
    s += __int_as_float(a);                       // xor 1
    int b = __builtin_amdgcn_update_dpp(0, __float_as_int(s), 0x4E, 0xF, 0xF, true);
    s += __int_as_float(b);                       // xor 2
    return s;
}

// --- one-time: psi fp32 -> psiB [k][m][uv] bf16 and psiT [j=k*4096+uv][m] --
__global__ __launch_bounds__(256) void prep_k(const float* __restrict__ psi,
                                              ushort_t* __restrict__ psiB,
                                              ushort_t* __restrict__ psiT) {
    int base = blockIdx.x * 2048 + threadIdx.x;
    for (int i = 0; i < 8; ++i) {
        int e = base + i * 256;                // e in [0, 2097152)
        float v = psi[e];
        ushort_t h = f2b(v);
        psiB[e] = h;
        int k = e >> 18;
        int r = e & 262143;
        int m = r >> 12;
        int uv = r & 4095;
        psiT[(size_t)k * 262144 + (size_t)uv * 64 + m] = h;
    }
}

// --- GEMM1: T[b][j] = sum_m y[b,m] * psiT[j,m].  D-rows <-> j. -------------
// grid 1024 = 512 j-windows x 2 b-halves (128 b).  18 KB LDS -> 8 wg/CU.
__global__ __launch_bounds__(256) void gemm1_k(const ushort_t* __restrict__ ybf,
                                               const ushort_t* __restrict__ psiT,
                                               ushort_t* __restrict__ Tbf) {
    __shared__ __align__(16) ushort_t Ls[128 * 72];   // [b 128][j 64] swizzled
    int wg = blockIdx.x;
    int j0 = (wg & 511) * 64;
    int bt = wg >> 9;                   // 0..1
    int tid = threadIdx.x;
    int wave = tid >> 6, lane = tid & 63;
    int rowi = lane & 15, q = lane >> 4;
    int b0w = bt * 128 + wave * 32;     // global b base of this wave

    f32x4 acc[4][2];
    const f32x4 zero = {0.f, 0.f, 0.f, 0.f};
    for (int ta = 0; ta < 4; ++ta)
        for (int tb = 0; tb < 2; ++tb) acc[ta][tb] = zero;

    for (int ks = 0; ks < 2; ++ks) {
        bf16x8 a[4], bb[2];
        for (int ta = 0; ta < 4; ++ta)
            a[ta] = *(const bf16x8*)(psiT + (size_t)(j0 + ta * 16 + rowi) * 64 +
                                     ks * 32 + q * 8);
        for (int tb = 0; tb < 2; ++tb)
            bb[tb] = *(const bf16x8*)(ybf + (size_t)(b0w + tb * 16 + rowi) * 64 +
                                      ks * 32 + q * 8);
        for (int ta = 0; ta < 4; ++ta)
            for (int tb = 0; tb < 2; ++tb)
                acc[ta][tb] = __builtin_amdgcn_mfma_f32_16x16x32_bf16(
                    a[ta], bb[tb], acc[ta][tb], 0, 0, 0);
    }
    // D[row=jfrag(q*4+r)][col=bfrag(rowi)] -> LDS (8-ushort chunks, swizzled)
    for (int ta = 0; ta < 4; ++ta)
        for (int tb = 0; tb < 2; ++tb) {
            int bl = wave * 32 + tb * 16 + rowi;      // local b in [0,128)
            int jl = ta * 16 + q * 4;
            uint_t lo = (uint_t)f2b(acc[ta][tb][0]) | ((uint_t)f2b(acc[ta][tb][1]) << 16);
            uint_t hi = (uint_t)f2b(acc[ta][tb][2]) | ((uint_t)f2b(acc[ta][tb][3]) << 16);
            int idx = bl * 72 + ((((jl >> 3) + 2 * bl) & 7) << 3) + (jl & 7);
            *(uint2*)&Ls[idx] = make_uint2(lo, hi);
        }
    __syncthreads();
    // coalesced stores: 8 lanes cover one b-row's 128B
    for (int pass = 0; pass < 4; ++pass) {
        int b = pass * 32 + (tid >> 3);               // local b
        int ch = tid & 7;
        uint4 v = *(const uint4*)&Ls[b * 72 + ch * 8];
        int x = (ch - 2 * b) & 7;
        *(uint4*)(Tbf + (size_t)(bt * 128 + b) * 32768 + j0 + x * 8) = v;
    }
}

// --- Krylov: per (b,k); T in registers; grad mode writes O over T. ---------
template <int NT>
__global__ __launch_bounds__(256) void krylov_k(const ushort_t* __restrict__ Tbf,
                                                const float* __restrict__ z0,
                                                const float* __restrict__ z1,
                                                ushort_t* __restrict__ Obf,
                                                float* __restrict__ out) {
    __shared__ float V[NT][64];
    __shared__ float U[NT][64];
    __shared__ float zz[64];
    int bid = blockIdx.x;
    int b = bid >> 3, k = bid & 7;
    int tid = threadIdx.x;
    int row = tid >> 2, p = tid & 3, c0 = p * 16;
    bool grad = (out == nullptr);

    const ushort_t* tbase = Tbf + (size_t)bid * 4096;
    float rowT[16];
    {
        uint4 ra = *(const uint4*)(tbase + row * 64 + c0);
        uint4 rb = *(const uint4*)(tbase + row * 64 + c0 + 8);
        uint_t wv[8] = {ra.x, ra.y, ra.z, ra.w, rb.x, rb.y, rb.z, rb.w};
        for (int i = 0; i < 8; ++i) {
            rowT[2 * i]     = __uint_as_float(wv[i] << 16);
            rowT[2 * i + 1] = __uint_as_float(wv[i] & 0xFFFF0000u);
        }
    }
    float colT[16];
    if (grad) {
#pragma unroll
        for (int i = 0; i < 16; ++i) colT[i] = b2f(tbase[(c0 + i) * 64 + row]);
    }
    if (tid < 64) {
        V[0][tid] = z0[(size_t)b * 512 + k * 64 + tid];
        zz[tid]   = z1[(size_t)b * 512 + k * 64 + tid];
    }
    __syncthreads();

    // v series
    for (int l = 1; l < NT; ++l) {
        const f32x4* vp = (const f32x4*)&V[l - 1][c0];
        f32x4 v0 = vp[0], v1 = vp[1], v2 = vp[2], v3 = vp[3];
        float s0 = 0.f, s1 = 0.f, s2 = 0.f, s3 = 0.f;
#pragma unroll
        for (int i = 0; i < 4; ++i) {
            s0 = fmaf(rowT[i], v0[i], s0);
            s1 = fmaf(rowT[4 + i], v1[i], s1);
            s2 = fmaf(rowT[8 + i], v2[i], s2);
            s3 = fmaf(rowT[12 + i], v3[i], s3);
        }
        float s = qsum4((s0 + s1) + (s2 + s3));
        if (p == 0) V[l][row] = s;
        __syncthreads();
    }

    if (!grad) {
        if (tid < 64) {
            float zh = 0.f;
#pragma unroll
            for (int l = 0; l < NT; ++l) zh = fmaf(INVF[l], V[l][tid], zh);
            out[(size_t)b * 512 + k * 64 + tid] = zh;
        }
        return;
    }

    if (tid < 64) {
        float zh = 0.f;
#pragma unroll
        for (int l = 0; l < NT; ++l) zh = fmaf(INVF[l], V[l][tid], zh);
        U[0][tid] = zh - zz[tid];
    }
    __syncthreads();

    // u series (T^T via colT)
    for (int j = 1; j < NT; ++j) {
        const f32x4* up = (const f32x4*)&U[j - 1][c0];
        f32x4 u0 = up[0], u1 = up[1], u2 = up[2], u3 = up[3];
        float s0 = 0.f, s1 = 0.f, s2 = 0.f, s3 = 0.f;
#pragma unroll
        for (int i = 0; i < 4; ++i) {
            s0 = fmaf(colT[i], u0[i], s0);
            s1 = fmaf(colT[4 + i], u1[i], s1);
            s2 = fmaf(colT[8 + i], u2[i], s2);
            s3 = fmaf(colT[12 + i], u3[i], s3);
        }
        float s = qsum4((s0 + s1) + (s2 + s3));
        if (p == 0) U[j][row] = s;
        __syncthreads();
    }

    // O[row][c0..c0+15] = sum_l W[l] * V[l][c]
    float W[NT];
#pragma unroll
    for (int l = 0; l < NT; ++l) {
        float w = 0.f;
#pragma unroll
        for (int j = 0; j < NT; ++j) w = fmaf(INVF[j + l + 1], U[j][row], w);
        W[l] = w;
    }
    float o[16];
#pragma unroll
    for (int i = 0; i < 16; ++i) o[i] = 0.f;
#pragma unroll
    for (int l = 0; l < NT; ++l) {
        const f32x4* vp = (const f32x4*)&V[l][c0];
        f32x4 a0 = vp[0], a1 = vp[1], a2 = vp[2], a3 = vp[3];
        float w = W[l];
#pragma unroll
        for (int i = 0; i < 4; ++i) {
            o[i]      = fmaf(w, a0[i], o[i]);
            o[4 + i]  = fmaf(w, a1[i], o[4 + i]);
            o[8 + i]  = fmaf(w, a2[i], o[8 + i]);
            o[12 + i] = fmaf(w, a3[i], o[12 + i]);
        }
    }
    uint_t ow[8];
#pragma unroll
    for (int i = 0; i < 8; ++i)
        ow[i] = (uint_t)f2b(o[2 * i]) | ((uint_t)f2b(o[2 * i + 1]) << 16);
    uint4* op = (uint4*)(Obf + (size_t)bid * 4096 + row * 64 + c0);
    op[0] = make_uint4(ow[0], ow[1], ow[2], ow[3]);
    op[1] = make_uint4(ow[4], ow[5], ow[6], ow[7]);
}

// --- GEMM2: gpart[kc][b][m] = sum_{uv in chunk} O[b][.] psiB[m][.] ---------
// grid 256 = 4 bt x 64 kc; 4 waves split the 512-long K-chunk; LDS reduce.
__global__ __launch_bounds__(256) void gemm2_k(const ushort_t* __restrict__ Obf,
                                               const ushort_t* __restrict__ psiB,
                                               float* __restrict__ gpart) {
    __shared__ __align__(16) float Lg[64 * 68];    // [b 64][m 64] stride 68
    int bt = blockIdx.x & 3;
    int kc = blockIdx.x >> 2;          // 0..63
    int k = kc >> 3;
    int uv0 = (kc & 7) * 512;
    int tid = threadIdx.x, wave = tid >> 6, lane = tid & 63;
    int rowi = lane & 15, q = lane >> 4;

    f32x4 acc[4][4];
    const f32x4 zero = {0.f, 0.f, 0.f, 0.f};
    for (int ta = 0; ta < 4; ++ta)
        for (int tb = 0; tb < 4; ++tb) acc[ta][tb] = zero;

    for (int ks = 0; ks < 4; ++ks) {
        int off = uv0 + wave * 128 + ks * 32 + q * 8;
        bf16x8 a[4], bb[4];
        for (int ta = 0; ta < 4; ++ta)
            a[ta] = *(const bf16x8*)(psiB + (size_t)k * 262144 +
                                     (size_t)(ta * 16 + rowi) * 4096 + off);
        for (int tb = 0; tb < 4; ++tb)
            bb[tb] = *(const bf16x8*)(Obf +
                                      (size_t)(bt * 64 + tb * 16 + rowi) * 32768 +
                                      k * 4096 + off);
        for (int ta = 0; ta < 4; ++ta)
            for (int tb = 0; tb < 4; ++tb)
                acc[ta][tb] = __builtin_amdgcn_mfma_f32_16x16x32_bf16(
                    a[ta], bb[tb], acc[ta][tb], 0, 0, 0);
    }
    // sequential inter-wave reduce: D[row=mfrag][col=bfrag]
    for (int w = 0; w < 4; ++w) {
        if (wave == w) {
            for (int ta = 0; ta < 4; ++ta)
                for (int tb = 0; tb < 4; ++tb) {
                    float* dst = &Lg[(tb * 16 + rowi) * 68 + ta * 16 + q * 4];
                    if (w == 0) *(f32x4*)dst = acc[ta][tb];
                    else {
                        f32x4 t = *(const f32x4*)dst;
                        t += acc[ta][tb];
                        *(f32x4*)dst = t;
                    }
                }
        }
        __syncthreads();
    }
    int b = tid >> 2, mq = tid & 3;
    float* gp = gpart + (size_t)kc * 16384 + (size_t)(bt * 64 + b) * 64 + mq * 16;
    const float* lp = &Lg[b * 68 + mq * 16];
    for (int i = 0; i < 4; ++i)
        *(f32x4*)(gp + 4 * i) = *(const f32x4*)(lp + 4 * i);
}

// --- FISTA: reduce 64 partials + prox step; maintain fp32 + bf16 state -----
__global__ __launch_bounds__(256) void fista_update(const float* __restrict__ gpart,
                                                    float* __restrict__ cb,
                                                    float* __restrict__ yb,
                                                    ushort_t* __restrict__ cbf,
                                                    ushort_t* __restrict__ ybf,
                                                    int iter) {
    int idx = blockIdx.x * 256 + threadIdx.x;
    float a0 = 0.f, a1 = 0.f, a2 = 0.f, a3 = 0.f;
#pragma unroll
    for (int p = 0; p < 64; p += 4) {
        a0 += gpart[(size_t)p * 16384 + idx];
        a1 += gpart[(size_t)(p + 1) * 16384 + idx];
        a2 += gpart[(size_t)(p + 2) * 16384 + idx];
        a3 += gpart[(size_t)(p + 3) * 16384 + idx];
    }
    float gv = (a0 + a1) + (a2 + a3);
    float t = 1.f;
    for (int s = 0; s < iter; ++s) t = 0.5f * (1.f + sqrtf(1.f + 4.f * t * t));
    float tn = 0.5f * (1.f + sqrtf(1.f + 4.f * t * t));
    float beta = (t - 1.f) / tn;
    float co = cb[idx], yo = yb[idx];
    float a = yo - 0.01f * gv;
    float thr = 0.01f * 0.05f;
    float cn = copysignf(fmaxf(fabsf(a) - thr, 0.f), a);
    float yn = cn + beta * (cn - co);
    cb[idx] = cn;
    yb[idx] = yn;
    cbf[idx] = f2b(cn);
    ybf[idx] = f2b(yn);
}

extern "C" void kernel_launch(void* const* d_in, const int* in_sizes, int n_in,
                              void* d_out, int out_size, void* d_ws, size_t ws_size,
                              hipStream_t stream) {
    const float* z0 = (const float*)d_in[0];
    const float* z1 = (const float*)d_in[1];
    const float* psi = (const float*)d_in[2];
    float* out = (float*)d_out;

    char* w = (char*)d_ws;
    ushort_t* TO    = (ushort_t*)(w);                 // 16,777,216  (T, then O)
    ushort_t* psiB  = (ushort_t*)(w + 16777216);      //  4,194,304
    ushort_t* psiT  = (ushort_t*)(w + 20971520);      //  4,194,304
    float*    gpart = (float*)(w + 25165824);         //  4,194,304  (64 partials)
    float*    cbuf  = (float*)(w + 29360128);         //     65,536
    float*    ybuf  = (float*)(w + 29425664);         //     65,536
    ushort_t* cbf   = (ushort_t*)(w + 29491200);      //     32,768
    ushort_t* ybf   = (ushort_t*)(w + 29523968);      //     32,768
    // total 29,556,736 B

    hipMemsetAsync(w + 29360128, 0, 196608, stream);  // zero c,y state

    prep_k<<<1024, 256, 0, stream>>>(psi, psiB, psiT);

    for (int it = 0; it < 20; ++it) {
        gemm1_k<<<1024, 256, 0, stream>>>(ybf, psiT, TO);
        krylov_k<6><<<2048, 256, 0, stream>>>(TO, z0, z1, TO, nullptr);
        gemm2_k<<<256, 256, 0, stream>>>(TO, psiB, gpart);
        fista_update<<<64, 256, 0, stream>>>(gpart, cbuf, ybuf, cbf, ybf, it);
    }

    gemm1_k<<<1024, 256, 0, stream>>>(cbf, psiT, TO);
    krylov_k<8><<<2048, 256, 0, stream>>>(TO, z0, z1, TO, out);
}